// Round 1
// baseline (130.140 us; speedup 1.0000x reference)
//
#include <hip/hip_runtime.h>
#include <hip/hip_bf16.h>
#include <stdint.h>

#define B_   32
#define C_   2048
#define HW_  196
#define OUT_ 512
#define KT_  128
#define NKT  (C_ / KT_)      // 16 k-tiles
#define BN_  112             // n-cols per block tile (nh=0: n 0..111, nh=1: n 84..195, overlap benign)
#define LDSS 132             // u16 per LDS row: 128 data + 4 pad -> +2 dword bank shift/row

typedef short short8 __attribute__((ext_vector_type(8)));
typedef float floatx4 __attribute__((ext_vector_type(4)));
typedef unsigned short u16;

__device__ __forceinline__ uint32_t pack_bf16(float a, float b) {
  union { __hip_bfloat162 h; uint32_t u; } c;
  c.h = __float22bfloat162_rn(make_float2(a, b));   // v_cvt_pk_bf16_f32
  return c.u;
}

// raw barrier: commit LDS writes (lgkmcnt) but do NOT drain vmcnt -> prefetch
// global loads stay in flight across the barrier.
#define BAR_SYNC() asm volatile("s_waitcnt lgkmcnt(0)\n\ts_barrier" ::: "memory")

// ---------------- prep: W fp32->bf16 (blocks <1024) + attention fallback ----------------
__global__ void prep_kernel(const float* __restrict__ w, u16* __restrict__ wbf,
                            const float* __restrict__ x,
                            const float* __restrict__ gamma,
                            float* __restrict__ y) {
  if (blockIdx.x < 1024) {
    int gid = blockIdx.x * 256 + threadIdx.x;
    float4 v = ((const float4*)w)[gid];
    ((uint2*)wbf)[gid] = make_uint2(pack_bf16(v.x, v.y), pack_bf16(v.z, v.w));
    return;
  }
  // full attention path, only if gamma != 0 (bench case: uniform early exit)
  float gm = gamma[0];
  if (gm == 0.0f || y == nullptr) return;
  __shared__ float qc[HW_];
  __shared__ float e[C_];
  __shared__ float red[256];
  int tid = threadIdx.x;
  for (int cRow = (int)blockIdx.x - 1024; cRow < C_; cRow += 256) {
    for (int b = 0; b < B_; ++b) {
      const float* q = x + (size_t)b * C_ * HW_;
      __syncthreads();
      for (int i = tid; i < HW_; i += 256) qc[i] = q[(size_t)cRow * HW_ + i];
      __syncthreads();
      for (int d = tid; d < C_; d += 256) {
        float s = 0.f;
        const float* qd = q + (size_t)d * HW_;
        for (int n = 0; n < HW_; ++n) s += qc[n] * qd[n];
        e[d] = s;
      }
      __syncthreads();
      float mn = 3.4e38f;
      for (int d = tid; d < C_; d += 256) mn = fminf(mn, e[d]);
      red[tid] = mn; __syncthreads();
      for (int s2 = 128; s2 > 0; s2 >>= 1) { if (tid < s2) red[tid] = fminf(red[tid], red[tid + s2]); __syncthreads(); }
      float emin = red[0];
      __syncthreads();
      float ps = 0.f;
      for (int d = tid; d < C_; d += 256) { float p = __expf(emin - e[d]); e[d] = p; ps += p; }
      red[tid] = ps; __syncthreads();
      for (int s2 = 128; s2 > 0; s2 >>= 1) { if (tid < s2) red[tid] += red[tid + s2]; __syncthreads(); }
      float S = red[0];
      __syncthreads();
      float invS = 1.f / S;
      for (int n = tid; n < HW_; n += 256) {
        float acc2 = 0.f;
        for (int d = 0; d < C_; ++d) acc2 += e[d] * q[(size_t)d * HW_ + n];
        y[((size_t)b * C_ + cRow) * HW_ + n] = gm * acc2 * invS + q[(size_t)cRow * HW_ + n];
      }
    }
  }
}

// ---------------- fused transpose+GEMM ----------------
// Grid 256 = 32 b x 2 nh x 4 ot. Block = 128 o x 112 n, 4 waves (each 32 o x 112 n, mt=2).
// Staging: fp32 x read coalesced (float2 over n), transpose in registers via cvt_pk,
// one k-contiguous b64 LDS write per (4c x n) quad. No xT intermediate, no DMA.
__global__ __launch_bounds__(256, 1) void conv_gemm(
    const float* __restrict__ x, const float* __restrict__ yws,
    const float* __restrict__ gamma, const u16* __restrict__ wbf,
    const float* __restrict__ bias, float* __restrict__ out, int have_y) {

  __shared__ __align__(16) u16 Bs[2][BN_ * LDSS];   // 2 x 28.9 KB double buffer

  const int tid  = threadIdx.x;
  const int wave = tid >> 6;
  const int lane = tid & 63;
  const int col  = lane & 15;
  const int quad = lane >> 4;

  const int bid  = blockIdx.x;
  const int xcd  = bid & 7;
  const int s    = bid >> 3;
  const int ot   = s & 3;
  const int gset = s >> 2;
  const int g    = gset * 8 + xcd;   // 4 ot-blocks of one (b,nh) panel share an XCD (L2 reuse)
  const int b    = g >> 1;
  const int nh   = g & 1;
  const int n0   = nh * (HW_ - BN_); // 0 or 84
  const int oBase= ot * 128;

  const float* src = (have_y && gamma[0] != 0.0f) ? yws : x;
  const float* panel = src + (size_t)b * C_ * HW_ + n0;

  // staging map: idx = i*256+tid -> (c4 = idx/56 in [0,32), np = idx%56 in [0,56))
  // loads: 4 rows (c=4*c4..+3) x float2 (n=2np,2np+1), rows via imm offsets 784/1568/2352 B
  int gOff[7], lOff[7];
#pragma unroll
  for (int i = 0; i < 7; ++i) {
    int idx = i * 256 + tid;
    int u = idx / 56;                 // c4 index
    int v = idx - u * 56;             // n-pair index
    gOff[i] = u * 4 * HW_ + 2 * v;    // float offset within panel
    lOff[i] = (2 * v) * LDSS + 4 * u; // u16 offset: row n=2v, chunk c4
  }

  // fragment row offsets: row n = nt*16+col, chunk (ks*8+quad*2) -> u16 ks*32+quad*8
  int rowOff[7];
#pragma unroll
  for (int nt = 0; nt < 7; ++nt) rowOff[nt] = (nt * 16 + col) * LDSS + quad * 8;

  const u16* aRow = wbf + (size_t)(oBase + wave * 32 + col) * C_ + quad * 8;

  floatx4 acc[2][7];
#pragma unroll
  for (int m = 0; m < 2; ++m)
#pragma unroll
    for (int nt = 0; nt < 7; ++nt) { floatx4 z = {0.f, 0.f, 0.f, 0.f}; acc[m][nt] = z; }

  float2 sv[7][4];     // staged x tile (56 VGPR)
  uint4  aR[8];        // A fragments for current tile: [m*4+ks]

  auto stageLoad = [&](int kt) {
    const float* p = panel + (size_t)kt * KT_ * HW_;
#pragma unroll
    for (int i = 0; i < 7; ++i) {
      const float* q = p + gOff[i];
#pragma unroll
      for (int r = 0; r < 4; ++r) sv[i][r] = *(const float2*)(q + r * HW_);
    }
  };
  auto loadA = [&](int kt) {
#pragma unroll
    for (int m = 0; m < 2; ++m)
#pragma unroll
      for (int ks = 0; ks < 4; ++ks)
        aR[m * 4 + ks] = *(const uint4*)(aRow + (size_t)m * 16 * C_ + kt * KT_ + ks * 32);
  };
  auto stageWrite = [&](u16* bb) {
    // compiler inserts counted s_waitcnt vmcnt(N) before first pack (A loads stay in flight)
#pragma unroll
    for (int i = 0; i < 7; ++i) {
      uint2 w0 = make_uint2(pack_bf16(sv[i][0].x, sv[i][1].x),
                            pack_bf16(sv[i][2].x, sv[i][3].x));
      uint2 w1 = make_uint2(pack_bf16(sv[i][0].y, sv[i][1].y),
                            pack_bf16(sv[i][2].y, sv[i][3].y));
      *(uint2*)(bb + lOff[i])        = w0;   // row 2v, c 4u..4u+3
      *(uint2*)(bb + lOff[i] + LDSS) = w1;   // row 2v+1
    }
  };
  auto phase = [&](const u16* bb) {
#pragma unroll
    for (int ks = 0; ks < 4; ++ks) {
      union { uint4 u; short8 v; } a0, a1;
      a0.u = aR[ks]; a1.u = aR[4 + ks];
#pragma unroll
      for (int nt = 0; nt < 7; ++nt) {
        const u16* fp = bb + rowOff[nt] + ks * 32;
        union { uint2 p[2]; short8 v; } bf;
        bf.p[0] = *(const uint2*)fp;        // k 8q..8q+3
        bf.p[1] = *(const uint2*)(fp + 4);  // k 8q+4..8q+7
        acc[0][nt] = __builtin_amdgcn_mfma_f32_16x16x32_bf16(a0.v, bf.v, acc[0][nt], 0, 0, 0);
        acc[1][nt] = __builtin_amdgcn_mfma_f32_16x16x32_bf16(a1.v, bf.v, acc[1][nt], 0, 0, 0);
      }
    }
  };

  // prologue: tile0 staged+written, tile1 loads in flight
  stageLoad(0);
  loadA(0);
  stageWrite(Bs[0]);
  stageLoad(1);
  BAR_SYNC();

  // steady state, one barrier per K-tile:
  //   phase(t) | loadA(t+1) | write buf(t+1) | issue loads(t+2) | barrier
  u16* cur = Bs[0]; u16* nxt = Bs[1];
  for (int kt = 0; kt < NKT; ++kt) {
    phase(cur);
    if (kt + 1 < NKT) {
      loadA(kt + 1);
      stageWrite(nxt);
      if (kt + 2 < NKT) stageLoad(kt + 2);
      BAR_SYNC();
      u16* t = cur; cur = nxt; nxt = t;
    }
  }

  // epilogue: D col = lane&15 (n), row = quad*4 + r (o); no masks (nh overlap covers tail)
  float* outb = out + (size_t)b * OUT_ * HW_ + n0;
#pragma unroll
  for (int m = 0; m < 2; ++m)
#pragma unroll
    for (int r = 0; r < 4; ++r) {
      int o = oBase + wave * 32 + m * 16 + quad * 4 + r;
      float bv = bias[o];
      float* orow = outb + (size_t)o * HW_;
#pragma unroll
      for (int nt = 0; nt < 7; ++nt)
        orow[nt * 16 + col] = acc[m][nt][r] + bv;
    }
}

extern "C" void kernel_launch(void* const* d_in, const int* in_sizes, int n_in,
                              void* d_out, int out_size, void* d_ws, size_t ws_size,
                              hipStream_t stream) {
  const float* x      = (const float*)d_in[0];
  const float* gamma  = (const float*)d_in[1];
  const float* conv_w = (const float*)d_in[2];
  const float* conv_b = (const float*)d_in[3];
  float* out = (float*)d_out;

  const size_t wbf_bytes = (size_t)OUT_ * C_ * sizeof(u16);        // 2 MiB
  const size_t y_bytes   = (size_t)B_ * C_ * HW_ * sizeof(float);  // 51.4 MiB
  u16*   wbf = (u16*)d_ws;
  float* yws = (float*)((char*)d_ws + wbf_bytes);
  int have_y = ws_size >= wbf_bytes + y_bytes;

  int prep_grid = have_y ? 1280 : 1024;    // 1024 wcvt blocks + 256 fallback blocks
  prep_kernel<<<dim3(prep_grid), dim3(256), 0, stream>>>(
      conv_w, wbf, x, gamma, have_y ? yws : nullptr);
  conv_gemm<<<dim3(256), dim3(256), 0, stream>>>(
      x, have_y ? yws : x, gamma, wbf, conv_b, out, have_y);
}